// Round 1
// baseline (1953.662 us; speedup 1.0000x reference)
//
#include <hip/hip_runtime.h>

// Problem constants (fixed by setup_inputs)
#define BATCH 8
#define CH 32
#define NPTS 65536
#define OCH 32
#define RES 32
#define R3 32768

// Workspace layout (float offsets)
#define OF_MEAN  0          // 24
#define OF_SCALE 32         // 8
#define OF_B1F   64         // 32
#define OF_B2F   96         // 32
#define OF_PBF   128        // 32
#define OF_WT1   1024       // 27648  wT[tap][o][c], BN-folded
#define OF_WT2   28672      // 27648
#define OF_PWF   56320      // 2048   pw[o][cc], BN-folded
#define OF_NORMX 65536      // 524288
#define OF_NORMY (65536 + 524288)
#define OF_NORMZ (65536 + 2*524288)
#define OF_INDS  (65536 + 3*524288)          // int32, 524288
#define OF_CNT   (65536 + 4*524288)          // 262144 floats (zeroed)
#define OF_SUMS  (OF_CNT + 262144)           // 8388608 floats (zeroed) -> avg in-place
#define OF_H1    (OF_SUMS + 8388608)         // 8388608
#define OF_H2    (OF_H1 + 8388608)           // 8388608
// total = 27,590,656 floats = ~105.3 MiB of d_ws

__global__ void k_prep(const float* __restrict__ c1w, const float* __restrict__ c1b,
                       const float* __restrict__ g1,  const float* __restrict__ bb1,
                       const float* __restrict__ c2w, const float* __restrict__ c2b,
                       const float* __restrict__ g2,  const float* __restrict__ bb2,
                       const float* __restrict__ pw,  const float* __restrict__ pb,
                       const float* __restrict__ gp,  const float* __restrict__ bbp,
                       float* __restrict__ ws) {
    int tid = threadIdx.x;
    float sq = sqrtf(1.0f + 1e-4f);
    for (int i = tid; i < 27648; i += 256) {
        int tap = i >> 10; int rem = i & 1023; int o = rem >> 5; int c = rem & 31;
        ws[OF_WT1 + i] = c1w[(o * 32 + c) * 27 + tap] * (g1[o] / sq);
        ws[OF_WT2 + i] = c2w[(o * 32 + c) * 27 + tap] * (g2[o] / sq);
    }
    for (int i = tid; i < 2048; i += 256) {
        int o = i >> 6;
        ws[OF_PWF + i] = pw[i] * (gp[o] / sq);
    }
    if (tid < 32) {
        ws[OF_B1F + tid] = c1b[tid] * (g1[tid] / sq) + bb1[tid];
        ws[OF_B2F + tid] = c2b[tid] * (g2[tid] / sq) + bb2[tid];
        ws[OF_PBF + tid] = pb[tid] * (gp[tid] / sq) + bbp[tid];
    }
}

// one block per (batch, axis): f64 accumulation -> mean error ~1e-9 (flip-safe)
__global__ void k_mean(const float* __restrict__ coords, float* __restrict__ ws) {
    __shared__ double sd[256];
    int ba = blockIdx.x;                       // 0..23 = b*3+axis
    const float* p = coords + (size_t)ba * NPTS;
    double acc = 0.0;
    for (int i = threadIdx.x; i < NPTS; i += 256) acc += (double)p[i];
    sd[threadIdx.x] = acc; __syncthreads();
    for (int s = 128; s > 0; s >>= 1) {
        if (threadIdx.x < s) sd[threadIdx.x] += sd[threadIdx.x + s];
        __syncthreads();
    }
    if (threadIdx.x == 0) ws[OF_MEAN + ba] = (float)(sd[0] / (double)NPTS);
}

// one block per batch: max ||c-mean||^2, then 2*sqrt (commutes with max exactly)
__global__ void k_scale(const float* __restrict__ coords, float* __restrict__ ws) {
    __shared__ float sd[256];
    int b = blockIdx.x;
    float mx = ws[OF_MEAN + b * 3 + 0];
    float my = ws[OF_MEAN + b * 3 + 1];
    float mz = ws[OF_MEAN + b * 3 + 2];
    const float* px = coords + (size_t)(b * 3 + 0) * NPTS;
    const float* py = coords + (size_t)(b * 3 + 1) * NPTS;
    const float* pz = coords + (size_t)(b * 3 + 2) * NPTS;
    float m = 0.0f;
    for (int i = threadIdx.x; i < NPTS; i += 256) {
        float dx = px[i] - mx, dy = py[i] - my, dz = pz[i] - mz;
        float s = __fadd_rn(__fadd_rn(__fmul_rn(dx, dx), __fmul_rn(dy, dy)), __fmul_rn(dz, dz));
        m = fmaxf(m, s);
    }
    sd[threadIdx.x] = m; __syncthreads();
    for (int s = 128; s > 0; s >>= 1) {
        if (threadIdx.x < s) sd[threadIdx.x] = fmaxf(sd[threadIdx.x], sd[threadIdx.x + s]);
        __syncthreads();
    }
    if (threadIdx.x == 0) ws[OF_SCALE + b] = 2.0f * sqrtf(sd[0]);
}

__global__ __launch_bounds__(256) void k_voxelize(const float* __restrict__ coords,
                                                  const float* __restrict__ features,
                                                  float* __restrict__ ws) {
    int gid = blockIdx.x * 256 + threadIdx.x;   // 524288
    int b = gid >> 16, p = gid & 65535;
    float sc = ws[OF_SCALE + b];
    int vox[3];
    #pragma unroll
    for (int a = 0; a < 3; ++a) {
        float val = coords[(size_t)((b * 3 + a) << 16) + p];
        float m = ws[OF_MEAN + b * 3 + a];
        float v = (val - m) / sc + 0.5f;
        v = v * 32.0f;
        v = fminf(fmaxf(v, 0.0f), 31.0f);
        ws[(a == 0 ? OF_NORMX : (a == 1 ? OF_NORMY : OF_NORMZ)) + gid] = v;
        vox[a] = (int)rintf(v);                  // round-half-even, matches jnp.round
    }
    int ind = (vox[0] * 32 + vox[1]) * 32 + vox[2];
    int* indsp = (int*)(ws + OF_INDS);
    indsp[gid] = ind;
    atomicAdd(ws + OF_CNT + (b << 15) + ind, 1.0f);
    float* sp = ws + OF_SUMS + ((size_t)((b << 15) + ind) << 5);
    #pragma unroll
    for (int c = 0; c < 32; ++c)
        atomicAdd(sp + c, features[(size_t)(((b << 5) + c) << 16) + p]);
}

__global__ void k_avg(float* __restrict__ ws) {
    int gid = blockIdx.x * 256 + threadIdx.x;   // 8388608
    int vb = gid >> 5;
    float d = fmaxf(ws[OF_CNT + vb], 1.0f);
    ws[OF_SUMS + gid] = ws[OF_SUMS + gid] / d;
}

// conv3d 3x3x3 + folded BN + LeakyReLU; channel-last grids; uniform weight
// addresses -> s_load (SGPR operand), FMA-bound.
__global__ __launch_bounds__(256) void k_conv(const float* __restrict__ in,
                                              float* __restrict__ out,
                                              const float* __restrict__ wT,
                                              const float* __restrict__ bias) {
    int t = blockIdx.x * 256 + threadIdx.x;     // 262144
    int b = t >> 15, v = t & 32767;
    int x = v >> 10, y = (v >> 5) & 31, z = v & 31;
    float acc[32];
    #pragma unroll
    for (int o = 0; o < 32; ++o) acc[o] = 0.0f;

    #pragma unroll 1
    for (int kd = 0; kd < 3; ++kd) {
        #pragma unroll 1
        for (int kh = 0; kh < 3; ++kh) {
            #pragma unroll 1
            for (int kw = 0; kw < 3; ++kw) {
                int xx = x + kd - 1, yy = y + kh - 1, zz = z + kw - 1;
                bool ok = ((unsigned)xx < 32u) & ((unsigned)yy < 32u) & ((unsigned)zz < 32u);
                if (ok) {
                    const float* ip = in + ((size_t)((b << 15) + ((xx << 10) + (yy << 5) + zz)) << 5);
                    float iv[32];
                    #pragma unroll
                    for (int k = 0; k < 8; ++k)
                        *(float4*)(iv + 4 * k) = ((const float4*)ip)[k];
                    int tap = (kd * 3 + kh) * 3 + kw;
                    const float* wp = wT + tap * 1024;   // uniform address
                    #pragma unroll
                    for (int o = 0; o < 32; ++o) {
                        float a = acc[o];
                        #pragma unroll
                        for (int c = 0; c < 32; ++c)
                            a = fmaf(iv[c], wp[o * 32 + c], a);
                        acc[o] = a;
                    }
                }
            }
        }
    }
    float* op = out + ((size_t)t << 5);
    #pragma unroll
    for (int o = 0; o < 32; ++o) {
        float yv = acc[o] + bias[o];
        op[o] = yv >= 0.0f ? yv : 0.1f * yv;
    }
}

// per point: center gather + 64->32 linear (+BN,ReLU) + trilinear devox + sum
__global__ __launch_bounds__(256) void k_final(const float* __restrict__ features,
                                               float* __restrict__ out,
                                               const float* __restrict__ ws) {
    int gid = blockIdx.x * 256 + threadIdx.x;   // 524288
    int b = gid >> 16, p = gid & 65535;
    const int* indsp = (const int*)(ws + OF_INDS);
    int ind = indsp[gid];
    const float* av = ws + OF_SUMS + ((size_t)((b << 15) + ind) << 5);
    float cen[32];
    #pragma unroll
    for (int k = 0; k < 8; ++k) *(float4*)(cen + 4 * k) = ((const float4*)av)[k];
    float xin[64];
    #pragma unroll
    for (int c = 0; c < 32; ++c) {
        float f = features[(size_t)(((b << 5) + c) << 16) + p];
        xin[c] = f - cen[c];
        xin[32 + c] = f;
    }
    float pacc[32];
    const float* pwp = ws + OF_PWF;
    #pragma unroll
    for (int o = 0; o < 32; ++o) {
        float a = ws[OF_PBF + o];
        #pragma unroll
        for (int cc = 0; cc < 64; ++cc)
            a = fmaf(xin[cc], pwp[o * 64 + cc], a);
        pacc[o] = fmaxf(a, 0.0f);                // ReLU
    }
    // trilinear devoxelize from h2 and accumulate
    float fx = ws[OF_NORMX + gid], fy = ws[OF_NORMY + gid], fz = ws[OF_NORMZ + gid];
    float x0 = floorf(fx), y0 = floorf(fy), z0 = floorf(fz);
    float tx = fx - x0, ty = fy - y0, tz = fz - z0;
    int ix0 = (int)x0, iy0 = (int)y0, iz0 = (int)z0;
    int ix1 = min(ix0 + 1, 31), iy1 = min(iy0 + 1, 31), iz1 = min(iz0 + 1, 31);
    const float* h2 = ws + OF_H2 + (((size_t)b << 15) << 5);
    #pragma unroll
    for (int dx = 0; dx < 2; ++dx)
    #pragma unroll
    for (int dy = 0; dy < 2; ++dy)
    #pragma unroll
    for (int dz = 0; dz < 2; ++dz) {
        int idx = ((dx ? ix1 : ix0) * 32 + (dy ? iy1 : iy0)) * 32 + (dz ? iz1 : iz0);
        float w8 = (dx ? tx : 1.0f - tx) * (dy ? ty : 1.0f - ty) * (dz ? tz : 1.0f - tz);
        const float* hp = h2 + ((size_t)idx << 5);
        float hv[32];
        #pragma unroll
        for (int k = 0; k < 8; ++k) *(float4*)(hv + 4 * k) = ((const float4*)hp)[k];
        #pragma unroll
        for (int o = 0; o < 32; ++o) pacc[o] = fmaf(w8, hv[o], pacc[o]);
    }
    #pragma unroll
    for (int o = 0; o < 32; ++o)
        out[(size_t)(((b << 5) + o) << 16) + p] = pacc[o];
}

extern "C" void kernel_launch(void* const* d_in, const int* in_sizes, int n_in,
                              void* d_out, int out_size, void* d_ws, size_t ws_size,
                              hipStream_t stream) {
    const float* features = (const float*)d_in[0];
    const float* coords   = (const float*)d_in[1];
    const float* c1w = (const float*)d_in[2];
    const float* c1b = (const float*)d_in[3];
    const float* g1  = (const float*)d_in[4];
    const float* bb1 = (const float*)d_in[5];
    const float* c2w = (const float*)d_in[6];
    const float* c2b = (const float*)d_in[7];
    const float* g2  = (const float*)d_in[8];
    const float* bb2 = (const float*)d_in[9];
    const float* pw  = (const float*)d_in[10];
    const float* pb  = (const float*)d_in[11];
    const float* gp  = (const float*)d_in[12];
    const float* bbp = (const float*)d_in[13];
    float* ws  = (float*)d_ws;
    float* out = (float*)d_out;

    hipLaunchKernelGGL(k_prep, dim3(1), dim3(256), 0, stream,
                       c1w, c1b, g1, bb1, c2w, c2b, g2, bb2, pw, pb, gp, bbp, ws);
    hipMemsetAsync(ws + OF_CNT, 0, (size_t)(262144 + 8388608) * sizeof(float), stream);
    hipLaunchKernelGGL(k_mean, dim3(24), dim3(256), 0, stream, coords, ws);
    hipLaunchKernelGGL(k_scale, dim3(8), dim3(256), 0, stream, coords, ws);
    hipLaunchKernelGGL(k_voxelize, dim3(2048), dim3(256), 0, stream, coords, features, ws);
    hipLaunchKernelGGL(k_avg, dim3(32768), dim3(256), 0, stream, ws);
    hipLaunchKernelGGL(k_conv, dim3(1024), dim3(256), 0, stream,
                       ws + OF_SUMS, ws + OF_H1, ws + OF_WT1, ws + OF_B1F);
    hipLaunchKernelGGL(k_conv, dim3(1024), dim3(256), 0, stream,
                       ws + OF_H1, ws + OF_H2, ws + OF_WT2, ws + OF_B2F);
    hipLaunchKernelGGL(k_final, dim3(2048), dim3(256), 0, stream, features, out, ws);
}

// Round 3
// 1174.873 us; speedup vs baseline: 1.6629x; 1.6629x over previous
//
#include <hip/hip_runtime.h>

// Problem constants (fixed by setup_inputs)
#define BATCH 8
#define CH 32
#define NPTS 65536
#define OCH 32
#define RES 32
#define R3 32768

// Workspace layout (float/int offsets into d_ws)
#define OF_MEAN  0          // 24 floats
#define OF_SCALE 32         // 8
#define OF_B1F   64         // 32
#define OF_B2F   96         // 32
#define OF_PBF   128        // 32
#define OF_WT1   1024       // 27648  wT[tap][o][c], BN-folded
#define OF_WT2   28672      // 27648
#define OF_PWF   56320      // 2048   pw[o][cc], BN-folded
#define OF_INDS  65536      // int 524288: global voxel id vb = (b<<15)+ind
#define OF_SLOT  (OF_INDS + 524288)    // int 524288
#define OF_LIST  (OF_SLOT + 524288)    // int 524288
#define OF_CNT   (OF_LIST + 524288)    // int 262144 (memset 0 each launch)
#define OF_START (OF_CNT + 262144)     // int 262144
#define OF_BLKSUM (OF_START + 262144)  // int 1024 (padded 4096)
#define OF_AVG   (OF_BLKSUM + 4096)    // 8388608 floats, channel-last [vb][32]
#define OF_H1    (OF_AVG + 8388608)    // 8388608
#define OF_H2    (OF_H1 + 8388608)     // 8388608
#define OF_FT    OF_H1                 // featT [b*65536+p][32] aliases H1+H2 (dead before conv1)
// total = 27,332,608 floats = 104.3 MiB

__global__ void k_prep(const float* __restrict__ c1w, const float* __restrict__ c1b,
                       const float* __restrict__ g1,  const float* __restrict__ bb1,
                       const float* __restrict__ c2w, const float* __restrict__ c2b,
                       const float* __restrict__ g2,  const float* __restrict__ bb2,
                       const float* __restrict__ pw,  const float* __restrict__ pb,
                       const float* __restrict__ gp,  const float* __restrict__ bbp,
                       float* __restrict__ ws) {
    int tid = threadIdx.x;
    float sq = sqrtf(1.0f + 1e-4f);
    for (int i = tid; i < 27648; i += 256) {
        int tap = i >> 10; int rem = i & 1023; int o = rem >> 5; int c = rem & 31;
        ws[OF_WT1 + i] = c1w[(o * 32 + c) * 27 + tap] * (g1[o] / sq);
        ws[OF_WT2 + i] = c2w[(o * 32 + c) * 27 + tap] * (g2[o] / sq);
    }
    for (int i = tid; i < 2048; i += 256) {
        int o = i >> 6;
        ws[OF_PWF + i] = pw[i] * (gp[o] / sq);
    }
    if (tid < 32) {
        ws[OF_B1F + tid] = c1b[tid] * (g1[tid] / sq) + bb1[tid];
        ws[OF_B2F + tid] = c2b[tid] * (g2[tid] / sq) + bb2[tid];
        ws[OF_PBF + tid] = pb[tid] * (gp[tid] / sq) + bbp[tid];
    }
}

// one block per (batch, axis): f64 accumulation -> mean error ~1e-9 (flip-safe)
__global__ void k_mean(const float* __restrict__ coords, float* __restrict__ ws) {
    __shared__ double sd[256];
    int ba = blockIdx.x;                       // 0..23 = b*3+axis
    const float* p = coords + (size_t)ba * NPTS;
    double acc = 0.0;
    for (int i = threadIdx.x; i < NPTS; i += 256) acc += (double)p[i];
    sd[threadIdx.x] = acc; __syncthreads();
    for (int s = 128; s > 0; s >>= 1) {
        if (threadIdx.x < s) sd[threadIdx.x] += sd[threadIdx.x + s];
        __syncthreads();
    }
    if (threadIdx.x == 0) ws[OF_MEAN + ba] = (float)(sd[0] / (double)NPTS);
}

// one block per batch: max ||c-mean||^2, then 2*sqrt (commutes with max exactly)
__global__ void k_scale(const float* __restrict__ coords, float* __restrict__ ws) {
    __shared__ float sd[256];
    int b = blockIdx.x;
    float mx = ws[OF_MEAN + b * 3 + 0];
    float my = ws[OF_MEAN + b * 3 + 1];
    float mz = ws[OF_MEAN + b * 3 + 2];
    const float* px = coords + (size_t)(b * 3 + 0) * NPTS;
    const float* py = coords + (size_t)(b * 3 + 1) * NPTS;
    const float* pz = coords + (size_t)(b * 3 + 2) * NPTS;
    float m = 0.0f;
    for (int i = threadIdx.x; i < NPTS; i += 256) {
        float dx = px[i] - mx, dy = py[i] - my, dz = pz[i] - mz;
        float s = __fadd_rn(__fadd_rn(__fmul_rn(dx, dx), __fmul_rn(dy, dy)), __fmul_rn(dz, dz));
        m = fmaxf(m, s);
    }
    sd[threadIdx.x] = m; __syncthreads();
    for (int s = 128; s > 0; s >>= 1) {
        if (threadIdx.x < s) sd[threadIdx.x] = fmaxf(sd[threadIdx.x], sd[threadIdx.x + s]);
        __syncthreads();
    }
    if (threadIdx.x == 0) ws[OF_SCALE + b] = 2.0f * sqrtf(sd[0]);
}

// features [b][c][p] -> featT [b*65536+p][c], 32x64 LDS tile transpose
__global__ __launch_bounds__(256) void k_transpose(const float* __restrict__ f,
                                                   float* __restrict__ ws) {
    __shared__ float t[32][65];
    int blk = blockIdx.x;                 // 8192: b = blk>>10, 64-point tile
    int b = blk >> 10;
    int p0 = (blk & 1023) << 6;
    int tid = threadIdx.x;
    #pragma unroll
    for (int it = 0; it < 8; ++it) {
        int e = it * 256 + tid; int c = e >> 6; int pp = e & 63;
        t[c][pp] = f[(size_t)(((b << 5) + c) << 16) + p0 + pp];
    }
    __syncthreads();
    #pragma unroll
    for (int it = 0; it < 8; ++it) {
        int e = it * 256 + tid; int pp = e >> 5; int c = e & 31;
        ws[OF_FT + ((size_t)((b << 16) + p0 + pp) << 5) + c] = t[c][pp];
    }
}

// per point: voxel id + slot via single int atomic (returns old count)
__global__ __launch_bounds__(256) void k_voxassign(const float* __restrict__ coords,
                                                   float* __restrict__ ws) {
    int gid = blockIdx.x * 256 + threadIdx.x;   // 524288
    int b = gid >> 16, p = gid & 65535;
    float sc = ws[OF_SCALE + b];
    int vox[3];
    #pragma unroll
    for (int a = 0; a < 3; ++a) {
        float val = coords[(size_t)((b * 3 + a) << 16) + p];
        float m = ws[OF_MEAN + b * 3 + a];
        float v = (val - m) / sc + 0.5f;
        v = v * 32.0f;
        v = fminf(fmaxf(v, 0.0f), 31.0f);
        vox[a] = (int)rintf(v);                  // round-half-even == jnp.round
    }
    int vb = (b << 15) + ((vox[0] * 32 + vox[1]) * 32 + vox[2]);
    int* wsi = (int*)ws;
    wsi[OF_INDS + gid] = vb;
    int slot = atomicAdd(wsi + OF_CNT + vb, 1);
    wsi[OF_SLOT + gid] = slot;
}

__global__ void k_scanA(float* __restrict__ ws) {
    __shared__ int s[256];
    int tid = threadIdx.x;
    const int* cnt = (const int*)ws + OF_CNT;
    s[tid] = cnt[blockIdx.x * 256 + tid];
    __syncthreads();
    for (int st = 128; st > 0; st >>= 1) {
        if (tid < st) s[tid] += s[tid + st];
        __syncthreads();
    }
    if (tid == 0) ((int*)ws)[OF_BLKSUM + blockIdx.x] = s[0];
}

__global__ void k_scanB(float* __restrict__ ws) {   // 1 block x 1024
    __shared__ int s[1024];
    int tid = threadIdx.x;
    int* bs = (int*)ws + OF_BLKSUM;
    int v = bs[tid];
    s[tid] = v; __syncthreads();
    for (int off = 1; off < 1024; off <<= 1) {
        int x = (tid >= off) ? s[tid - off] : 0;
        __syncthreads();
        s[tid] += x;
        __syncthreads();
    }
    bs[tid] = s[tid] - v;                            // exclusive
}

__global__ void k_scanC(float* __restrict__ ws) {
    __shared__ int s[256];
    int tid = threadIdx.x;
    int gid = blockIdx.x * 256 + tid;
    int v = ((const int*)ws)[OF_CNT + gid];
    s[tid] = v; __syncthreads();
    for (int off = 1; off < 256; off <<= 1) {
        int x = (tid >= off) ? s[tid - off] : 0;
        __syncthreads();
        s[tid] += x;
        __syncthreads();
    }
    ((int*)ws)[OF_START + gid] = ((const int*)ws)[OF_BLKSUM + blockIdx.x] + s[tid] - v;
}

__global__ __launch_bounds__(256) void k_scatter(float* __restrict__ ws) {
    int gid = blockIdx.x * 256 + threadIdx.x;   // 524288
    int* wsi = (int*)ws;
    int vb = wsi[OF_INDS + gid];
    int slot = wsi[OF_SLOT + gid];
    wsi[OF_LIST + wsi[OF_START + vb] + slot] = gid;
}

// one wave per voxel: gather its points from featT, average, write channel-last
__global__ __launch_bounds__(256) void k_sum(float* __restrict__ ws) {
    int t = blockIdx.x * 256 + threadIdx.x;     // 16.7M threads = 262144 waves
    int vb = t >> 6;
    int lane = t & 63;
    int half = lane >> 5, c = lane & 31;
    const int* wsi = (const int*)ws;
    int n = wsi[OF_CNT + vb];
    int s0 = wsi[OF_START + vb];
    const int* list = (const int*)ws + OF_LIST;
    float acc = 0.0f;
    for (int j = half; j < n; j += 2) {
        int pt = list[s0 + j];
        acc += ws[OF_FT + ((size_t)pt << 5) + c];
    }
    acc += __shfl_xor(acc, 32, 64);
    if (half == 0)
        ws[OF_AVG + ((size_t)vb << 5) + c] = acc / fmaxf((float)n, 1.0f);
}

// conv3d 3x3x3 + folded BN + LeakyReLU; channel-last grids; uniform weight
// addresses -> SGPR operands, FMA-bound.
__global__ __launch_bounds__(256) void k_conv(const float* __restrict__ in,
                                              float* __restrict__ out,
                                              const float* __restrict__ wT,
                                              const float* __restrict__ bias) {
    int t = blockIdx.x * 256 + threadIdx.x;     // 262144
    int b = t >> 15, v = t & 32767;
    int x = v >> 10, y = (v >> 5) & 31, z = v & 31;
    float acc[32];
    #pragma unroll
    for (int o = 0; o < 32; ++o) acc[o] = 0.0f;

    #pragma unroll 1
    for (int kd = 0; kd < 3; ++kd) {
        #pragma unroll 1
        for (int kh = 0; kh < 3; ++kh) {
            #pragma unroll 1
            for (int kw = 0; kw < 3; ++kw) {
                int xx = x + kd - 1, yy = y + kh - 1, zz = z + kw - 1;
                bool ok = ((unsigned)xx < 32u) & ((unsigned)yy < 32u) & ((unsigned)zz < 32u);
                if (ok) {
                    const float* ip = in + ((size_t)((b << 15) + ((xx << 10) + (yy << 5) + zz)) << 5);
                    float iv[32];
                    #pragma unroll
                    for (int k = 0; k < 8; ++k)
                        *(float4*)(iv + 4 * k) = ((const float4*)ip)[k];
                    int tap = (kd * 3 + kh) * 3 + kw;
                    const float* wp = wT + tap * 1024;   // uniform address
                    #pragma unroll
                    for (int o = 0; o < 32; ++o) {
                        float a = acc[o];
                        #pragma unroll
                        for (int c = 0; c < 32; ++c)
                            a = fmaf(iv[c], wp[o * 32 + c], a);
                        acc[o] = a;
                    }
                }
            }
        }
    }
    float* op = out + ((size_t)t << 5);
    #pragma unroll
    for (int o = 0; o < 32; ++o) {
        float yv = acc[o] + bias[o];
        op[o] = yv >= 0.0f ? yv : 0.1f * yv;
    }
}

// per point: center gather + 64->32 linear (+BN,ReLU) + trilinear devox + sum
__global__ __launch_bounds__(256) void k_final(const float* __restrict__ features,
                                               const float* __restrict__ coords,
                                               float* __restrict__ out,
                                               const float* __restrict__ ws) {
    int gid = blockIdx.x * 256 + threadIdx.x;   // 524288
    int b = gid >> 16, p = gid & 65535;
    const int* wsi = (const int*)ws;
    int vb = wsi[OF_INDS + gid];
    const float* av = ws + OF_AVG + ((size_t)vb << 5);
    float cen[32];
    #pragma unroll
    for (int k = 0; k < 8; ++k) *(float4*)(cen + 4 * k) = ((const float4*)av)[k];
    float xin[64];
    #pragma unroll
    for (int c = 0; c < 32; ++c) {
        float f = features[(size_t)(((b << 5) + c) << 16) + p];
        xin[c] = f - cen[c];
        xin[32 + c] = f;
    }
    float pacc[32];
    const float* pwp = ws + OF_PWF;
    #pragma unroll
    for (int o = 0; o < 32; ++o) {
        float a = ws[OF_PBF + o];
        #pragma unroll
        for (int cc = 0; cc < 64; ++cc)
            a = fmaf(xin[cc], pwp[o * 64 + cc], a);
        pacc[o] = fmaxf(a, 0.0f);                // ReLU
    }
    // recompute normalized coords (bit-identical to k_voxassign's expressions)
    float sc = ws[OF_SCALE + b];
    float vxyz[3];
    #pragma unroll
    for (int a = 0; a < 3; ++a) {
        float val = coords[(size_t)((b * 3 + a) << 16) + p];
        float m = ws[OF_MEAN + b * 3 + a];
        float v = (val - m) / sc + 0.5f;
        v = v * 32.0f;
        v = fminf(fmaxf(v, 0.0f), 31.0f);
        vxyz[a] = v;
    }
    float x0 = floorf(vxyz[0]), y0 = floorf(vxyz[1]), z0 = floorf(vxyz[2]);
    float tx = vxyz[0] - x0, ty = vxyz[1] - y0, tz = vxyz[2] - z0;
    int ix0 = (int)x0, iy0 = (int)y0, iz0 = (int)z0;
    int ix1 = min(ix0 + 1, 31), iy1 = min(iy0 + 1, 31), iz1 = min(iz0 + 1, 31);
    const float* h2 = ws + OF_H2 + (((size_t)b << 15) << 5);
    #pragma unroll
    for (int dx = 0; dx < 2; ++dx)
    #pragma unroll
    for (int dy = 0; dy < 2; ++dy)
    #pragma unroll
    for (int dz = 0; dz < 2; ++dz) {
        int idx = ((dx ? ix1 : ix0) * 32 + (dy ? iy1 : iy0)) * 32 + (dz ? iz1 : iz0);
        float w8 = (dx ? tx : 1.0f - tx) * (dy ? ty : 1.0f - ty) * (dz ? tz : 1.0f - tz);
        const float* hp = h2 + ((size_t)idx << 5);
        float hv[32];
        #pragma unroll
        for (int k = 0; k < 8; ++k) *(float4*)(hv + 4 * k) = ((const float4*)hp)[k];
        #pragma unroll
        for (int o = 0; o < 32; ++o) pacc[o] = fmaf(w8, hv[o], pacc[o]);
    }
    #pragma unroll
    for (int o = 0; o < 32; ++o)
        out[(size_t)(((b << 5) + o) << 16) + p] = pacc[o];
}

extern "C" void kernel_launch(void* const* d_in, const int* in_sizes, int n_in,
                              void* d_out, int out_size, void* d_ws, size_t ws_size,
                              hipStream_t stream) {
    const float* features = (const float*)d_in[0];
    const float* coords   = (const float*)d_in[1];
    const float* c1w = (const float*)d_in[2];
    const float* c1b = (const float*)d_in[3];
    const float* g1  = (const float*)d_in[4];
    const float* bb1 = (const float*)d_in[5];
    const float* c2w = (const float*)d_in[6];
    const float* c2b = (const float*)d_in[7];
    const float* g2  = (const float*)d_in[8];
    const float* bb2 = (const float*)d_in[9];
    const float* pw  = (const float*)d_in[10];
    const float* pb  = (const float*)d_in[11];
    const float* gp  = (const float*)d_in[12];
    const float* bbp = (const float*)d_in[13];
    float* ws  = (float*)d_ws;
    float* out = (float*)d_out;

    hipLaunchKernelGGL(k_prep, dim3(1), dim3(256), 0, stream,
                       c1w, c1b, g1, bb1, c2w, c2b, g2, bb2, pw, pb, gp, bbp, ws);
    hipMemsetAsync(ws + OF_CNT, 0, (size_t)262144 * sizeof(int), stream);
    hipLaunchKernelGGL(k_mean, dim3(24), dim3(256), 0, stream, coords, ws);
    hipLaunchKernelGGL(k_scale, dim3(8), dim3(256), 0, stream, coords, ws);
    hipLaunchKernelGGL(k_transpose, dim3(8192), dim3(256), 0, stream, features, ws);
    hipLaunchKernelGGL(k_voxassign, dim3(2048), dim3(256), 0, stream, coords, ws);
    hipLaunchKernelGGL(k_scanA, dim3(1024), dim3(256), 0, stream, ws);
    hipLaunchKernelGGL(k_scanB, dim3(1), dim3(1024), 0, stream, ws);
    hipLaunchKernelGGL(k_scanC, dim3(1024), dim3(256), 0, stream, ws);
    hipLaunchKernelGGL(k_scatter, dim3(2048), dim3(256), 0, stream, ws);
    hipLaunchKernelGGL(k_sum, dim3(65536), dim3(256), 0, stream, ws);
    hipLaunchKernelGGL(k_conv, dim3(1024), dim3(256), 0, stream,
                       ws + OF_AVG, ws + OF_H1, ws + OF_WT1, ws + OF_B1F);
    hipLaunchKernelGGL(k_conv, dim3(1024), dim3(256), 0, stream,
                       ws + OF_H1, ws + OF_H2, ws + OF_WT2, ws + OF_B2F);
    hipLaunchKernelGGL(k_final, dim3(2048), dim3(256), 0, stream, features, coords, out, ws);
}